// Round 3
// baseline (265.830 us; speedup 1.0000x reference)
//
#include <hip/hip_runtime.h>

#define BB 32
#define LL 2048
#define DD 768
#define VV 32000
#define NSEG 16

// ---------------------------------------------------------------------------
// K1: one block per row (grid=32, block=256). O(L) via LDS histogram:
// 32000 16-bit counters packed 2-per-u32 (64000 B). Each thread owns 8
// contiguous tokens. Computes per-token weight, compacts valid (w,l) pairs
// via block scan, and the row norm — single block per row, no global atomics.
// ---------------------------------------------------------------------------
__global__ __launch_bounds__(256) void weights_kernel(
    const int* __restrict__ ids, const int* __restrict__ mask,
    const float* __restrict__ idf, const float* __restrict__ alpha_p,
    float* __restrict__ wc, int* __restrict__ lc,
    int* __restrict__ nv_ws, float* __restrict__ inv_ws)
{
    __shared__ unsigned int hist[VV / 2];   // 64000 B, packed 2x16-bit counts
    __shared__ int scan_s[256];

    const int tid = threadIdx.x;
    const int b   = blockIdx.x;

    for (int i = tid; i < VV / 2; i += 256) hist[i] = 0u;

    const int4* ids4 = (const int4*)(ids  + b * LL);
    const int4* msk4 = (const int4*)(mask + b * LL);
    const int4 ia = ids4[2 * tid], ib = ids4[2 * tid + 1];
    const int4 ma = msk4[2 * tid], mb = msk4[2 * tid + 1];
    const int idv[8] = {ia.x, ia.y, ia.z, ia.w, ib.x, ib.y, ib.z, ib.w};
    const int mv[8]  = {ma.x, ma.y, ma.z, ma.w, mb.x, mb.y, mb.z, mb.w};

    __syncthreads();                        // hist zeroed

    int c_t = 0;
    #pragma unroll
    for (int k = 0; k < 8; ++k) {
        if (mv[k]) {
            atomicAdd(&hist[idv[k] >> 1], 1u << ((idv[k] & 1) * 16));
            c_t++;
        }
    }

    // Block inclusive scan of per-thread valid counts (barriers also order
    // the histogram atomics before the reads below).
    scan_s[tid] = c_t;
    __syncthreads();
    for (int off = 1; off < 256; off <<= 1) {
        const int v   = scan_s[tid];
        const int add = (tid >= off) ? scan_s[tid - off] : 0;
        __syncthreads();
        scan_s[tid] = v + add;
        __syncthreads();
    }
    const int excl        = scan_s[tid] - c_t;
    const int total_valid = scan_s[255];
    __syncthreads();

    const float nvf   = fmaxf((float)total_valid, 1.0f);
    const float alpha = alpha_p[0];

    float wsum = 0.0f;
    float wv[8];
    #pragma unroll
    for (int k = 0; k < 8; ++k) {
        const int id        = idv[k];
        const unsigned raw  = hist[id >> 1];
        const int cnt       = (raw >> ((id & 1) * 16)) & 0xffff;
        const float tf      = (float)cnt / nvf;
        const float w       = (1.0f + alpha * tf * idf[id]) * (float)(mv[k] != 0);
        wv[k] = w;
        wsum += w;
    }

    int pos = b * LL + excl;
    #pragma unroll
    for (int k = 0; k < 8; ++k) {
        if (mv[k]) { wc[pos] = wv[k]; lc[pos] = tid * 8 + k; pos++; }
    }

    #pragma unroll
    for (int off = 32; off; off >>= 1) wsum += __shfl_down(wsum, off, 64);
    if ((tid & 63) == 0) scan_s[tid >> 6] = __float_as_int(wsum);
    __syncthreads();
    if (tid == 0) {
        const float t = __int_as_float(scan_s[0]) + __int_as_float(scan_s[1])
                      + __int_as_float(scan_s[2]) + __int_as_float(scan_s[3]);
        inv_ws[b] = 1.0f / fmaxf(t, 1e-12f);
        nv_ws[b]  = total_valid;
    }
}

// ---------------------------------------------------------------------------
// K2: pooling over the compacted token list. Each block owns a CONTIGUOUS
// chunk (<=128 tokens) of its row's compacted list, staged to LDS up front —
// the address-producing load becomes a hoistable ~120-cyc LDS read instead of
// a ~500-cyc global load. Waves split the chunk stride-4, unrolled x2:
// 6 independent 1KB-coalesced loads in flight per wave (48 KB/CU >> the
// ~9 KB Little's-law requirement at 900-cyc HBM latency).
// grid = (NSEG, B), block = 256.
// ---------------------------------------------------------------------------
__global__ __launch_bounds__(256) void pool_kernel(
    const float* __restrict__ h, const float* __restrict__ wc,
    const int* __restrict__ lc, const int* __restrict__ nv_ws,
    float* __restrict__ part)
{
    __shared__ float w_s[128];
    __shared__ int   l_s[128];
    __shared__ float red[4 * DD];           // 12 KB

    const int tid  = threadIdx.x;
    const int wave = tid >> 6, lane = tid & 63;
    const int b = blockIdx.y, s = blockIdx.x;

    const int nv    = nv_ws[b];
    const int chunk = (nv + NSEG - 1) / NSEG;          // <= 128
    const int lo    = s * chunk;
    const int cnt   = max(0, min(lo + chunk, nv) - lo);

    if (tid < cnt) {
        w_s[tid] = wc[b * LL + lo + tid];
        l_s[tid] = lc[b * LL + lo + tid];
    }
    __syncthreads();

    const float* hb = h + (size_t)b * (LL * DD);
    float4 a0 = {0,0,0,0}, a1 = {0,0,0,0}, a2 = {0,0,0,0};

    int i = wave;
    for (; i + 4 < cnt; i += 8) {
        const float wA = w_s[i],     wB = w_s[i + 4];
        const float4* pA = (const float4*)(hb + (size_t)l_s[i]     * DD);
        const float4* pB = (const float4*)(hb + (size_t)l_s[i + 4] * DD);
        const float4 vA0 = pA[lane], vA1 = pA[64 + lane], vA2 = pA[128 + lane];
        const float4 vB0 = pB[lane], vB1 = pB[64 + lane], vB2 = pB[128 + lane];
        a0.x = fmaf(vA0.x, wA, a0.x); a0.y = fmaf(vA0.y, wA, a0.y);
        a0.z = fmaf(vA0.z, wA, a0.z); a0.w = fmaf(vA0.w, wA, a0.w);
        a1.x = fmaf(vA1.x, wA, a1.x); a1.y = fmaf(vA1.y, wA, a1.y);
        a1.z = fmaf(vA1.z, wA, a1.z); a1.w = fmaf(vA1.w, wA, a1.w);
        a2.x = fmaf(vA2.x, wA, a2.x); a2.y = fmaf(vA2.y, wA, a2.y);
        a2.z = fmaf(vA2.z, wA, a2.z); a2.w = fmaf(vA2.w, wA, a2.w);
        a0.x = fmaf(vB0.x, wB, a0.x); a0.y = fmaf(vB0.y, wB, a0.y);
        a0.z = fmaf(vB0.z, wB, a0.z); a0.w = fmaf(vB0.w, wB, a0.w);
        a1.x = fmaf(vB1.x, wB, a1.x); a1.y = fmaf(vB1.y, wB, a1.y);
        a1.z = fmaf(vB1.z, wB, a1.z); a1.w = fmaf(vB1.w, wB, a1.w);
        a2.x = fmaf(vB2.x, wB, a2.x); a2.y = fmaf(vB2.y, wB, a2.y);
        a2.z = fmaf(vB2.z, wB, a2.z); a2.w = fmaf(vB2.w, wB, a2.w);
    }
    for (; i < cnt; i += 4) {
        const float w = w_s[i];
        const float4* p = (const float4*)(hb + (size_t)l_s[i] * DD);
        const float4 v0 = p[lane], v1 = p[64 + lane], v2 = p[128 + lane];
        a0.x = fmaf(v0.x, w, a0.x); a0.y = fmaf(v0.y, w, a0.y);
        a0.z = fmaf(v0.z, w, a0.z); a0.w = fmaf(v0.w, w, a0.w);
        a1.x = fmaf(v1.x, w, a1.x); a1.y = fmaf(v1.y, w, a1.y);
        a1.z = fmaf(v1.z, w, a1.z); a1.w = fmaf(v1.w, w, a1.w);
        a2.x = fmaf(v2.x, w, a2.x); a2.y = fmaf(v2.y, w, a2.y);
        a2.z = fmaf(v2.z, w, a2.z); a2.w = fmaf(v2.w, w, a2.w);
    }

    float4* r = (float4*)(red + wave * DD);
    r[lane] = a0; r[64 + lane] = a1; r[128 + lane] = a2;
    __syncthreads();
    for (int k = tid; k < DD; k += 256) {
        part[((size_t)b * NSEG + s) * DD + k] =
            red[k] + red[DD + k] + red[2 * DD + k] + red[3 * DD + k];
    }
}

// ---------------------------------------------------------------------------
// K3: sum NSEG partials per (b,d), scale by 1/norm. grid = 96, block = 256.
// ---------------------------------------------------------------------------
__global__ __launch_bounds__(256) void finalize_kernel(
    const float* __restrict__ part, const float* __restrict__ inv_ws,
    float* __restrict__ out)
{
    const int idx = blockIdx.x * 256 + threadIdx.x;   // 0..24575
    const int b = idx / DD, d = idx - b * DD;
    float s = 0.0f;
    #pragma unroll
    for (int k = 0; k < NSEG; ++k) s += part[((size_t)b * NSEG + k) * DD + d];
    out[idx] = s * inv_ws[b];
}

extern "C" void kernel_launch(void* const* d_in, const int* in_sizes, int n_in,
                              void* d_out, int out_size, void* d_ws, size_t ws_size,
                              hipStream_t stream)
{
    const float* h     = (const float*)d_in[0];   // [B,L,D] fp32
    const int*   mask  = (const int*)  d_in[1];   // [B,L]
    const int*   ids   = (const int*)  d_in[2];   // [B,L]
    const float* idf   = (const float*)d_in[3];   // [V]
    const float* alpha = (const float*)d_in[4];   // scalar
    float*       out   = (float*)d_out;           // [B,D]

    float* wc   = (float*)d_ws;                   // B*L floats
    int*   lc   = (int*)(wc + BB * LL);           // B*L ints
    int*   nv   = lc + BB * LL;                   // B ints
    float* inv  = (float*)(nv + BB);              // B floats
    float* part = inv + BB;                       // B*NSEG*D floats (1.5 MB)

    weights_kernel<<<BB, 256, 0, stream>>>(ids, mask, idf, alpha, wc, lc, nv, inv);
    pool_kernel<<<dim3(NSEG, BB), 256, 0, stream>>>(h, wc, lc, nv, part);
    finalize_kernel<<<(BB * DD) / 256, 256, 0, stream>>>(part, inv, out);
}

// Round 4
// 262.979 us; speedup vs baseline: 1.0108x; 1.0108x over previous
//
#include <hip/hip_runtime.h>

#define BB 32
#define LL 2048
#define DD 768
#define VV 32000
#define NSEG 32

// ---------------------------------------------------------------------------
// K1: one block per row (grid=32, block=256). O(L) via LDS histogram:
// 32000 16-bit counters packed 2-per-u32 (64000 B). Each thread owns 8
// contiguous tokens. Computes per-token weight, compacts valid (w,l) pairs
// via block scan, and 1/norm — single block per row, no global atomics.
// Also zeroes out[] (harness poisons it 0xAA) so K2 can atomicAdd into it.
// ---------------------------------------------------------------------------
__global__ __launch_bounds__(256) void weights_kernel(
    const int* __restrict__ ids, const int* __restrict__ mask,
    const float* __restrict__ idf, const float* __restrict__ alpha_p,
    float* __restrict__ wc, int* __restrict__ lc,
    int* __restrict__ nv_ws, float* __restrict__ inv_ws,
    float* __restrict__ out)
{
    __shared__ unsigned int hist[VV / 2];   // 64000 B, packed 2x16-bit counts
    __shared__ int scan_s[256];

    const int tid = threadIdx.x;
    const int b   = blockIdx.x;

    // Zero this row's slice of out (K2 accumulates into it atomically).
    out[b * DD + tid]       = 0.0f;
    out[b * DD + 256 + tid] = 0.0f;
    out[b * DD + 512 + tid] = 0.0f;

    for (int i = tid; i < VV / 2; i += 256) hist[i] = 0u;

    const int4* ids4 = (const int4*)(ids  + b * LL);
    const int4* msk4 = (const int4*)(mask + b * LL);
    const int4 ia = ids4[2 * tid], ib = ids4[2 * tid + 1];
    const int4 ma = msk4[2 * tid], mb = msk4[2 * tid + 1];
    const int idv[8] = {ia.x, ia.y, ia.z, ia.w, ib.x, ib.y, ib.z, ib.w};
    const int mv[8]  = {ma.x, ma.y, ma.z, ma.w, mb.x, mb.y, mb.z, mb.w};

    __syncthreads();                        // hist zeroed

    int c_t = 0;
    #pragma unroll
    for (int k = 0; k < 8; ++k) {
        if (mv[k]) {
            atomicAdd(&hist[idv[k] >> 1], 1u << ((idv[k] & 1) * 16));
            c_t++;
        }
    }

    // Block inclusive scan of per-thread valid counts (barriers also order
    // the histogram atomics before the reads below).
    scan_s[tid] = c_t;
    __syncthreads();
    for (int off = 1; off < 256; off <<= 1) {
        const int v   = scan_s[tid];
        const int add = (tid >= off) ? scan_s[tid - off] : 0;
        __syncthreads();
        scan_s[tid] = v + add;
        __syncthreads();
    }
    const int excl        = scan_s[tid] - c_t;
    const int total_valid = scan_s[255];
    __syncthreads();

    const float nvf   = fmaxf((float)total_valid, 1.0f);
    const float alpha = alpha_p[0];

    float wsum = 0.0f;
    float wv[8];
    #pragma unroll
    for (int k = 0; k < 8; ++k) {
        const int id        = idv[k];
        const unsigned raw  = hist[id >> 1];
        const int cnt       = (raw >> ((id & 1) * 16)) & 0xffff;
        const float tf      = (float)cnt / nvf;
        const float w       = (1.0f + alpha * tf * idf[id]) * (float)(mv[k] != 0);
        wv[k] = w;
        wsum += w;
    }

    int pos = b * LL + excl;
    #pragma unroll
    for (int k = 0; k < 8; ++k) {
        if (mv[k]) { wc[pos] = wv[k]; lc[pos] = tid * 8 + k; pos++; }
    }

    #pragma unroll
    for (int off = 32; off; off >>= 1) wsum += __shfl_down(wsum, off, 64);
    if ((tid & 63) == 0) scan_s[tid >> 6] = __float_as_int(wsum);
    __syncthreads();
    if (tid == 0) {
        const float t = __int_as_float(scan_s[0]) + __int_as_float(scan_s[1])
                      + __int_as_float(scan_s[2]) + __int_as_float(scan_s[3]);
        inv_ws[b] = 1.0f / fmaxf(t, 1e-12f);
        nv_ws[b]  = total_valid;
    }
}

// ---------------------------------------------------------------------------
// K2: pooling over the compacted token list, fused finalize. Each block owns
// a contiguous chunk (<=64 tokens) of its row's compacted list, staged to LDS
// up front. Waves split the chunk stride-4, unrolled x2: 6 independent
// 1KB-coalesced loads in flight per wave. Block-level LDS reduce, then one
// atomicAdd per output element with 1/norm folded in (out pre-zeroed by K1;
// 32 adds/element, fp32-commutative well within tolerance).
// grid = (NSEG=32, B) = 1024 blocks -> 4 blocks/CU, block = 256.
// ---------------------------------------------------------------------------
__global__ __launch_bounds__(256) void pool_kernel(
    const float* __restrict__ h, const float* __restrict__ wc,
    const int* __restrict__ lc, const int* __restrict__ nv_ws,
    const float* __restrict__ inv_ws, float* __restrict__ out)
{
    __shared__ float w_s[64];
    __shared__ int   l_s[64];
    __shared__ float red[4 * DD];           // 12 KB

    const int tid  = threadIdx.x;
    const int wave = tid >> 6, lane = tid & 63;
    const int b = blockIdx.y, s = blockIdx.x;

    const int nv    = nv_ws[b];
    const int chunk = (nv + NSEG - 1) / NSEG;          // <= 64
    const int lo    = s * chunk;
    const int cnt   = max(0, min(lo + chunk, nv) - lo);

    if (tid < cnt) {
        w_s[tid] = wc[b * LL + lo + tid];
        l_s[tid] = lc[b * LL + lo + tid];
    }
    __syncthreads();

    const float* hb = h + (size_t)b * (LL * DD);
    float4 a0 = {0,0,0,0}, a1 = {0,0,0,0}, a2 = {0,0,0,0};

    int i = wave;
    for (; i + 4 < cnt; i += 8) {
        const float wA = w_s[i],     wB = w_s[i + 4];
        const float4* pA = (const float4*)(hb + (size_t)l_s[i]     * DD);
        const float4* pB = (const float4*)(hb + (size_t)l_s[i + 4] * DD);
        const float4 vA0 = pA[lane], vA1 = pA[64 + lane], vA2 = pA[128 + lane];
        const float4 vB0 = pB[lane], vB1 = pB[64 + lane], vB2 = pB[128 + lane];
        a0.x = fmaf(vA0.x, wA, a0.x); a0.y = fmaf(vA0.y, wA, a0.y);
        a0.z = fmaf(vA0.z, wA, a0.z); a0.w = fmaf(vA0.w, wA, a0.w);
        a1.x = fmaf(vA1.x, wA, a1.x); a1.y = fmaf(vA1.y, wA, a1.y);
        a1.z = fmaf(vA1.z, wA, a1.z); a1.w = fmaf(vA1.w, wA, a1.w);
        a2.x = fmaf(vA2.x, wA, a2.x); a2.y = fmaf(vA2.y, wA, a2.y);
        a2.z = fmaf(vA2.z, wA, a2.z); a2.w = fmaf(vA2.w, wA, a2.w);
        a0.x = fmaf(vB0.x, wB, a0.x); a0.y = fmaf(vB0.y, wB, a0.y);
        a0.z = fmaf(vB0.z, wB, a0.z); a0.w = fmaf(vB0.w, wB, a0.w);
        a1.x = fmaf(vB1.x, wB, a1.x); a1.y = fmaf(vB1.y, wB, a1.y);
        a1.z = fmaf(vB1.z, wB, a1.z); a1.w = fmaf(vB1.w, wB, a1.w);
        a2.x = fmaf(vB2.x, wB, a2.x); a2.y = fmaf(vB2.y, wB, a2.y);
        a2.z = fmaf(vB2.z, wB, a2.z); a2.w = fmaf(vB2.w, wB, a2.w);
    }
    for (; i < cnt; i += 4) {
        const float w = w_s[i];
        const float4* p = (const float4*)(hb + (size_t)l_s[i] * DD);
        const float4 v0 = p[lane], v1 = p[64 + lane], v2 = p[128 + lane];
        a0.x = fmaf(v0.x, w, a0.x); a0.y = fmaf(v0.y, w, a0.y);
        a0.z = fmaf(v0.z, w, a0.z); a0.w = fmaf(v0.w, w, a0.w);
        a1.x = fmaf(v1.x, w, a1.x); a1.y = fmaf(v1.y, w, a1.y);
        a1.z = fmaf(v1.z, w, a1.z); a1.w = fmaf(v1.w, w, a1.w);
        a2.x = fmaf(v2.x, w, a2.x); a2.y = fmaf(v2.y, w, a2.y);
        a2.z = fmaf(v2.z, w, a2.z); a2.w = fmaf(v2.w, w, a2.w);
    }

    float4* r = (float4*)(red + wave * DD);
    r[lane] = a0; r[64 + lane] = a1; r[128 + lane] = a2;
    __syncthreads();

    const float inv = inv_ws[b];
    for (int k = tid; k < DD; k += 256) {
        const float v = red[k] + red[DD + k] + red[2 * DD + k] + red[3 * DD + k];
        atomicAdd(&out[b * DD + k], v * inv);
    }
}

extern "C" void kernel_launch(void* const* d_in, const int* in_sizes, int n_in,
                              void* d_out, int out_size, void* d_ws, size_t ws_size,
                              hipStream_t stream)
{
    const float* h     = (const float*)d_in[0];   // [B,L,D] fp32
    const int*   mask  = (const int*)  d_in[1];   // [B,L]
    const int*   ids   = (const int*)  d_in[2];   // [B,L]
    const float* idf   = (const float*)d_in[3];   // [V]
    const float* alpha = (const float*)d_in[4];   // scalar
    float*       out   = (float*)d_out;           // [B,D]

    float* wc  = (float*)d_ws;                    // B*L floats
    int*   lc  = (int*)(wc + BB * LL);            // B*L ints
    int*   nv  = lc + BB * LL;                    // B ints
    float* inv = (float*)(nv + BB);               // B floats

    weights_kernel<<<BB, 256, 0, stream>>>(ids, mask, idf, alpha, wc, lc, nv, inv, out);
    pool_kernel<<<dim3(NSEG, BB), 256, 0, stream>>>(h, wc, lc, nv, inv, out);
}

// Round 5
// 260.556 us; speedup vs baseline: 1.0202x; 1.0093x over previous
//
#include <hip/hip_runtime.h>

#define BB 32
#define LL 2048
#define DD 768
#define VV 32000
#define NSEG 32

// ---------------------------------------------------------------------------
// K1: one 512-thread block per row (grid=32). O(L) via LDS histogram:
// 32000 16-bit counters packed 2-per-u32 (64000 B). Each thread owns 4
// contiguous tokens (one int4 load each for ids/mask). Scan is wave-shuffle
// based: 3 barriers total (vs 16+ for Hillis-Steele). idf gather is hoisted
// to overlap its scattered-load latency with the histogram phase.
// Also zeroes out[] (harness poisons 0xAA) so K2 can atomicAdd into it.
// ---------------------------------------------------------------------------
__global__ __launch_bounds__(512) void weights_kernel(
    const int* __restrict__ ids, const int* __restrict__ mask,
    const float* __restrict__ idf, const float* __restrict__ alpha_p,
    float* __restrict__ wc, int* __restrict__ lc,
    int* __restrict__ nv_ws, float* __restrict__ inv_ws,
    float* __restrict__ out)
{
    __shared__ unsigned int hist[VV / 2];   // 64000 B, packed 2x16-bit counts
    __shared__ int   wtot[8];
    __shared__ float wsum_s[8];

    const int tid  = threadIdx.x;
    const int lane = tid & 63, wave = tid >> 6;     // 8 waves
    const int b    = blockIdx.x;

    // Zero this row's slice of out (K2 accumulates into it atomically).
    for (int k = tid; k < DD; k += 512) out[b * DD + k] = 0.0f;

    for (int i = tid; i < VV / 2; i += 512) hist[i] = 0u;

    const int4 ia = ((const int4*)(ids  + b * LL))[tid];
    const int4 ma = ((const int4*)(mask + b * LL))[tid];
    const int idv[4] = {ia.x, ia.y, ia.z, ia.w};
    const int mv[4]  = {ma.x, ma.y, ma.z, ma.w};

    // Hoisted idf gather — latency overlaps hist zero + atomics below.
    float idfv[4];
    #pragma unroll
    for (int k = 0; k < 4; ++k) idfv[k] = idf[idv[k]];

    __syncthreads();                        // barrier 1: hist zeroed

    int c_t = 0;
    #pragma unroll
    for (int k = 0; k < 4; ++k) {
        if (mv[k]) {
            atomicAdd(&hist[idv[k] >> 1], 1u << ((idv[k] & 1) * 16));
            c_t++;
        }
    }

    // Wave-level inclusive scan of c_t (no barriers).
    int incl = c_t;
    #pragma unroll
    for (int off = 1; off < 64; off <<= 1) {
        const int n = __shfl_up(incl, off, 64);
        if (lane >= off) incl += n;
    }
    if (lane == 63) wtot[wave] = incl;
    __syncthreads();                        // barrier 2: orders hist atomics + wtot

    int wpre = 0, total_valid = 0;
    #pragma unroll
    for (int w = 0; w < 8; ++w) {
        const int t = wtot[w];
        if (w < wave) wpre += t;
        total_valid += t;
    }
    const int excl = wpre + incl - c_t;

    const float nvf   = fmaxf((float)total_valid, 1.0f);
    const float alpha = alpha_p[0];

    float wsum = 0.0f;
    float wv[4];
    #pragma unroll
    for (int k = 0; k < 4; ++k) {
        const int id       = idv[k];
        const unsigned raw = hist[id >> 1];
        const int cnt      = (raw >> ((id & 1) * 16)) & 0xffff;
        const float tf     = (float)cnt / nvf;
        const float w      = (1.0f + alpha * tf * idfv[k]) * (float)(mv[k] != 0);
        wv[k] = w;
        wsum += w;
    }

    int pos = b * LL + excl;
    #pragma unroll
    for (int k = 0; k < 4; ++k) {
        if (mv[k]) { wc[pos] = wv[k]; lc[pos] = tid * 4 + k; pos++; }
    }

    // Row norm: wave shuffle-reduce, then thread 0 combines 8 wave sums.
    #pragma unroll
    for (int off = 32; off; off >>= 1) wsum += __shfl_down(wsum, off, 64);
    if (lane == 0) wsum_s[wave] = wsum;
    __syncthreads();                        // barrier 3
    if (tid == 0) {
        float t = 0.0f;
        #pragma unroll
        for (int w = 0; w < 8; ++w) t += wsum_s[w];
        inv_ws[b] = 1.0f / fmaxf(t, 1e-12f);
        nv_ws[b]  = total_valid;
    }
}

// ---------------------------------------------------------------------------
// K2: pooling over the compacted token list, fused finalize. Each block owns
// a contiguous chunk (<=64 tokens) of its row's compacted list, staged to LDS
// up front. Waves split the chunk stride-4, unrolled x2: 6 independent
// 1KB-coalesced loads in flight per wave. Block-level LDS reduce, then one
// atomicAdd per output element with 1/norm folded in (out pre-zeroed by K1).
// grid = (NSEG=32, B) = 1024 blocks -> 4 blocks/CU, block = 256.
// At its BW floor (~101 MB valid-row reads) — R3 inner-loop tuning was neutral.
// ---------------------------------------------------------------------------
__global__ __launch_bounds__(256) void pool_kernel(
    const float* __restrict__ h, const float* __restrict__ wc,
    const int* __restrict__ lc, const int* __restrict__ nv_ws,
    const float* __restrict__ inv_ws, float* __restrict__ out)
{
    __shared__ float w_s[64];
    __shared__ int   l_s[64];
    __shared__ float red[4 * DD];           // 12 KB

    const int tid  = threadIdx.x;
    const int wave = tid >> 6, lane = tid & 63;
    const int b = blockIdx.y, s = blockIdx.x;

    const int nv    = nv_ws[b];
    const int chunk = (nv + NSEG - 1) / NSEG;          // <= 64
    const int lo    = s * chunk;
    const int cnt   = max(0, min(lo + chunk, nv) - lo);

    if (tid < cnt) {
        w_s[tid] = wc[b * LL + lo + tid];
        l_s[tid] = lc[b * LL + lo + tid];
    }
    __syncthreads();

    const float* hb = h + (size_t)b * (LL * DD);
    float4 a0 = {0,0,0,0}, a1 = {0,0,0,0}, a2 = {0,0,0,0};

    int i = wave;
    for (; i + 4 < cnt; i += 8) {
        const float wA = w_s[i],     wB = w_s[i + 4];
        const float4* pA = (const float4*)(hb + (size_t)l_s[i]     * DD);
        const float4* pB = (const float4*)(hb + (size_t)l_s[i + 4] * DD);
        const float4 vA0 = pA[lane], vA1 = pA[64 + lane], vA2 = pA[128 + lane];
        const float4 vB0 = pB[lane], vB1 = pB[64 + lane], vB2 = pB[128 + lane];
        a0.x = fmaf(vA0.x, wA, a0.x); a0.y = fmaf(vA0.y, wA, a0.y);
        a0.z = fmaf(vA0.z, wA, a0.z); a0.w = fmaf(vA0.w, wA, a0.w);
        a1.x = fmaf(vA1.x, wA, a1.x); a1.y = fmaf(vA1.y, wA, a1.y);
        a1.z = fmaf(vA1.z, wA, a1.z); a1.w = fmaf(vA1.w, wA, a1.w);
        a2.x = fmaf(vA2.x, wA, a2.x); a2.y = fmaf(vA2.y, wA, a2.y);
        a2.z = fmaf(vA2.z, wA, a2.z); a2.w = fmaf(vA2.w, wA, a2.w);
        a0.x = fmaf(vB0.x, wB, a0.x); a0.y = fmaf(vB0.y, wB, a0.y);
        a0.z = fmaf(vB0.z, wB, a0.z); a0.w = fmaf(vB0.w, wB, a0.w);
        a1.x = fmaf(vB1.x, wB, a1.x); a1.y = fmaf(vB1.y, wB, a1.y);
        a1.z = fmaf(vB1.z, wB, a1.z); a1.w = fmaf(vB1.w, wB, a1.w);
        a2.x = fmaf(vB2.x, wB, a2.x); a2.y = fmaf(vB2.y, wB, a2.y);
        a2.z = fmaf(vB2.z, wB, a2.z); a2.w = fmaf(vB2.w, wB, a2.w);
    }
    for (; i < cnt; i += 4) {
        const float w = w_s[i];
        const float4* p = (const float4*)(hb + (size_t)l_s[i] * DD);
        const float4 v0 = p[lane], v1 = p[64 + lane], v2 = p[128 + lane];
        a0.x = fmaf(v0.x, w, a0.x); a0.y = fmaf(v0.y, w, a0.y);
        a0.z = fmaf(v0.z, w, a0.z); a0.w = fmaf(v0.w, w, a0.w);
        a1.x = fmaf(v1.x, w, a1.x); a1.y = fmaf(v1.y, w, a1.y);
        a1.z = fmaf(v1.z, w, a1.z); a1.w = fmaf(v1.w, w, a1.w);
        a2.x = fmaf(v2.x, w, a2.x); a2.y = fmaf(v2.y, w, a2.y);
        a2.z = fmaf(v2.z, w, a2.z); a2.w = fmaf(v2.w, w, a2.w);
    }

    float4* r = (float4*)(red + wave * DD);
    r[lane] = a0; r[64 + lane] = a1; r[128 + lane] = a2;
    __syncthreads();

    const float inv = inv_ws[b];
    for (int k = tid; k < DD; k += 256) {
        const float v = red[k] + red[DD + k] + red[2 * DD + k] + red[3 * DD + k];
        atomicAdd(&out[b * DD + k], v * inv);
    }
}

extern "C" void kernel_launch(void* const* d_in, const int* in_sizes, int n_in,
                              void* d_out, int out_size, void* d_ws, size_t ws_size,
                              hipStream_t stream)
{
    const float* h     = (const float*)d_in[0];   // [B,L,D] fp32
    const int*   mask  = (const int*)  d_in[1];   // [B,L]
    const int*   ids   = (const int*)  d_in[2];   // [B,L]
    const float* idf   = (const float*)d_in[3];   // [V]
    const float* alpha = (const float*)d_in[4];   // scalar
    float*       out   = (float*)d_out;           // [B,D]

    float* wc  = (float*)d_ws;                    // B*L floats
    int*   lc  = (int*)(wc + BB * LL);            // B*L ints
    int*   nv  = lc + BB * LL;                    // B ints
    float* inv = (float*)(nv + BB);               // B floats

    weights_kernel<<<BB, 512, 0, stream>>>(ids, mask, idf, alpha, wc, lc, nv, inv, out);
    pool_kernel<<<dim3(NSEG, BB), 256, 0, stream>>>(h, wc, lc, nv, inv, out);
}